// Round 7
// baseline (67.193 us; speedup 1.0000x reference)
//
#include <hip/hip_runtime.h>
#include <hip/hip_bf16.h>

// GaussianVoxelizer: B=1, G=128 gaussians, F=16 features, N=100*100*8=80000.
// Sum/count formulation (== reference's incremental masked mean).
//
// R7 design: R6's single-launch gather + survivor-only staging, but with
// 2 voxels per thread (512 voxels/block, 157 blocks) to halve the number of
// per-block setup chains (cull loads -> ballot -> barrier -> staging), which
// dominate self-time at ~1 block/CU. Survivor params (LDS broadcast) are
// amortized over two voxel evaluations; stores stay coalesced.
//
// Inputs (setup_inputs order):
//   d_in[0] grid_coords (N,3) f32   (unused -- centers recomputed as
//                                    (i+0.5)*0.8+lo, bit-identical to ref)
//   d_in[1] means3d     (1,G,3) f32
//   d_in[2] opacities   (1,G,1) f32
//   d_in[3] features    (1,G,F) f32
//   d_in[4] covariances (1,G,3,3) f32
// Output: dens (N) f32 followed by feats (N,F) f32, concatenated flat.

#define GV_F 16
#define GV_SX 100
#define GV_SY 100
#define GV_SZ 8
#define GV_SYZ (GV_SY * GV_SZ)   // 800
#define GV_LOX (-40.0f)
#define GV_LOY (-40.0f)
#define GV_LOZ (-1.0f)
#define GV_VOX 0.8f
#define GV_GMAX 128
#define GV_VPB 512                // voxels per block (2 per thread)

__global__ __launch_bounds__(256)
void GaussianVoxelizer_40467181863368_kernel(
    const float* __restrict__ means,  // (G,3)
    const float* __restrict__ opac,   // (G)
    const float* __restrict__ feats,  // (G,F)
    const float* __restrict__ covs,   // (G,9)
    float* __restrict__ out_dens,     // (N)
    float* __restrict__ out_feat,     // (N,F)
    int N, int G)
{
    // compacted survivor params: [0..2]=mean, [3]=opacity,
    // [4..9]=k00,k01,k02,k11,k12,k22 (coeffs of -0.5*maha, off-diags doubled)
    __shared__ float s_p[GV_GMAX][10];
    __shared__ float s_f[GV_GMAX][GV_F];   // opacity * features (compacted)
    __shared__ unsigned long long s_mask[4];

    const int t = threadIdx.x;
    const int wv = t >> 6;
    const int n0 = blockIdx.x * GV_VPB;
    const int nlast = min(n0 + GV_VPB - 1, N - 1);

    // ---- Block AABB over voxel CENTERS ----
    const int ix_lo = n0 / GV_SYZ;
    const int ix_hi = nlast / GV_SYZ;
    const float bx0 = ((float)ix_lo + 0.5f) * GV_VOX + GV_LOX;
    const float bx1 = ((float)ix_hi + 0.5f) * GV_VOX + GV_LOX;
    float by0, by1;
    if (ix_lo == ix_hi) {
        const int iy0b = (n0 - ix_lo * GV_SYZ) >> 3;          // /GV_SZ
        const int iy1b = (nlast - ix_hi * GV_SYZ) >> 3;
        by0 = ((float)iy0b + 0.5f) * GV_VOX + GV_LOY;
        by1 = ((float)iy1b + 0.5f) * GV_VOX + GV_LOY;
    } else {                                                   // straddles x boundary
        by0 = 0.5f * GV_VOX + GV_LOY;
        by1 = ((float)(GV_SY - 1) + 0.5f) * GV_VOX + GV_LOY;
    }
    const float bz0 = 0.5f * GV_VOX + GV_LOZ;                  // -0.6
    const float bz1 = ((float)(GV_SZ - 1) + 0.5f) * GV_VOX + GV_LOZ;  // 5.0

    // ---- Cull: mean + cov only (same 6 KB read by every block -> L2-hot) ----
    bool flag = false;
    float mx = 0.f, my = 0.f, mz = 0.f;
    float c00 = 0.f, c01 = 0.f, c02 = 0.f, c11 = 0.f, c12 = 0.f, c22 = 0.f;
    if (t < G) {
        mx = means[t * 3 + 0];
        my = means[t * 3 + 1];
        mz = means[t * 3 + 2];
        c00 = covs[t * 9 + 0];
        c01 = covs[t * 9 + 1];
        c02 = covs[t * 9 + 2];
        c11 = covs[t * 9 + 4];
        c12 = covs[t * 9 + 5];
        c22 = covs[t * 9 + 8];
        const float rx = 2.0f * sqrtf(c00) + 1e-3f;   // support bound + fp pad
        const float ry = 2.0f * sqrtf(c11) + 1e-3f;
        const float rz = 2.0f * sqrtf(c22) + 1e-3f;
        flag = (mx - rx <= bx1) && (mx + rx >= bx0) &&
               (my - ry <= by1) && (my + ry >= by0) &&
               (mz - rz <= bz1) && (mz + rz >= bz0);
    }

    const unsigned long long m = __ballot(flag);
    if ((t & 63) == 0) s_mask[wv] = m;
    __syncthreads();

    // ---- Survivor-only staging into compacted slots (ascending g) ----
    if (flag) {
        int pos = 0;
        #pragma unroll
        for (int i = 0; i < 4; ++i) pos += (i < wv) ? __popcll(s_mask[i]) : 0;
        const unsigned long long lt = (t & 63) ? ((1ull << (t & 63)) - 1ull) : 0ull;
        pos += __popcll(m & lt);

        // inverse covariance via adjugate (cov = A*A^T + 0.1I, SPD, det>=1e-3)
        const float m00 = c11 * c22 - c12 * c12;
        const float m01 = c02 * c12 - c01 * c22;
        const float m02 = c01 * c12 - c02 * c11;
        const float det = c00 * m00 + c01 * m01 + c02 * m02;
        const float s = -0.5f / det;
        const float op = opac[t];

        s_p[pos][0] = mx;
        s_p[pos][1] = my;
        s_p[pos][2] = mz;
        s_p[pos][3] = op;
        s_p[pos][4] = m00 * s;
        s_p[pos][5] = m01 * (2.0f * s);
        s_p[pos][6] = m02 * (2.0f * s);
        s_p[pos][7] = (c00 * c22 - c02 * c02) * s;
        s_p[pos][8] = (c01 * c02 - c00 * c12) * (2.0f * s);
        s_p[pos][9] = (c00 * c11 - c01 * c01) * s;

        const float4* fr = (const float4*)(feats + (size_t)t * GV_F);
        float4* fw = (float4*)(&s_f[pos][0]);
        #pragma unroll
        for (int q = 0; q < 4; ++q) {
            float4 v = fr[q];
            v.x *= op; v.y *= op; v.z *= op; v.w *= op;
            fw[q] = v;
        }
    }
    __syncthreads();
    const int L = __popcll(s_mask[0]) + __popcll(s_mask[1]) +
                  __popcll(s_mask[2]) + __popcll(s_mask[3]);

    // ---- Per-voxel evaluation: 2 voxels per thread (nA = n0+t, nB = nA+256) ----
    const int nA = n0 + t;
    const int nB = nA + 256;
    if (nA >= N) return;

    const int ixA = nA / GV_SYZ;
    const int remA = nA - ixA * GV_SYZ;
    const float cxA = ((float)ixA + 0.5f) * GV_VOX + GV_LOX;
    const float cyA = ((float)(remA >> 3) + 0.5f) * GV_VOX + GV_LOY;
    const float czA = ((float)(remA & 7) + 0.5f) * GV_VOX + GV_LOZ;

    const bool hasB = (nB < N);
    const int ixB = hasB ? (nB / GV_SYZ) : 0;
    const int remB = hasB ? (nB - ixB * GV_SYZ) : 0;
    const float cxB = ((float)ixB + 0.5f) * GV_VOX + GV_LOX;
    const float cyB = ((float)(remB >> 3) + 0.5f) * GV_VOX + GV_LOY;
    const float czB = ((float)(remB & 7) + 0.5f) * GV_VOX + GV_LOZ;

    float cntA = 0.0f, sdA = 0.0f;
    float cntB = 0.0f, sdB = 0.0f;
    float sfA[GV_F], sfB[GV_F];
    #pragma unroll
    for (int j = 0; j < GV_F; ++j) { sfA[j] = 0.0f; sfB[j] = 0.0f; }

    for (int l = 0; l < L; ++l) {               // l block-uniform -> LDS broadcast
        const float pmx = s_p[l][0], pmy = s_p[l][1], pmz = s_p[l][2];
        const float pop = s_p[l][3];
        const float k00 = s_p[l][4], k01 = s_p[l][5], k02 = s_p[l][6];
        const float k11 = s_p[l][7], k12 = s_p[l][8], k22 = s_p[l][9];

        // voxel A
        {
            const float dx = cxA - pmx, dy = cyA - pmy, dz = czA - pmz;
            float a = k00 * dx;
            a = fmaf(k01, dy, a);
            a = fmaf(k02, dz, a);
            float tt = a * dx;
            float b = k11 * dy;
            b = fmaf(k12, dz, b);
            tt = fmaf(b, dy, tt);
            tt = fmaf(k22 * dz, dz, tt);
            if (tt >= -2.0f) {                  // maha <= 4
                const float w = __expf(tt);
                cntA += 1.0f;
                sdA = fmaf(pop, w, sdA);
                #pragma unroll
                for (int j = 0; j < GV_F; ++j) sfA[j] = fmaf(s_f[l][j], w, sfA[j]);
            }
        }
        // voxel B
        if (hasB) {
            const float dx = cxB - pmx, dy = cyB - pmy, dz = czB - pmz;
            float a = k00 * dx;
            a = fmaf(k01, dy, a);
            a = fmaf(k02, dz, a);
            float tt = a * dx;
            float b = k11 * dy;
            b = fmaf(k12, dz, b);
            tt = fmaf(b, dy, tt);
            tt = fmaf(k22 * dz, dz, tt);
            if (tt >= -2.0f) {
                const float w = __expf(tt);
                cntB += 1.0f;
                sdB = fmaf(pop, w, sdB);
                #pragma unroll
                for (int j = 0; j < GV_F; ++j) sfB[j] = fmaf(s_f[l][j], w, sfB[j]);
            }
        }
    }

    {
        const float inv_c = (cntA > 0.0f) ? (1.0f / cntA) : 0.0f;
        out_dens[nA] = sdA * inv_c;
        float4* fo = (float4*)(out_feat + (size_t)nA * GV_F);
        #pragma unroll
        for (int q = 0; q < 4; ++q) {
            fo[q] = make_float4(sfA[4 * q + 0] * inv_c,
                                sfA[4 * q + 1] * inv_c,
                                sfA[4 * q + 2] * inv_c,
                                sfA[4 * q + 3] * inv_c);
        }
    }
    if (hasB) {
        const float inv_c = (cntB > 0.0f) ? (1.0f / cntB) : 0.0f;
        out_dens[nB] = sdB * inv_c;
        float4* fo = (float4*)(out_feat + (size_t)nB * GV_F);
        #pragma unroll
        for (int q = 0; q < 4; ++q) {
            fo[q] = make_float4(sfB[4 * q + 0] * inv_c,
                                sfB[4 * q + 1] * inv_c,
                                sfB[4 * q + 2] * inv_c,
                                sfB[4 * q + 3] * inv_c);
        }
    }
}

extern "C" void kernel_launch(void* const* d_in, const int* in_sizes, int n_in,
                              void* d_out, int out_size, void* d_ws, size_t ws_size,
                              hipStream_t stream) {
    const float* means = (const float*)d_in[1];
    const float* opac  = (const float*)d_in[2];
    const float* feats = (const float*)d_in[3];
    const float* covs  = (const float*)d_in[4];

    const int N = in_sizes[0] / 3;       // 80000
    const int G = in_sizes[2];           // B*G = 128 (B=1)

    float* out_dens = (float*)d_out;         // (N)
    float* out_feat = (float*)d_out + N;     // (N,F)

    const int grid_n = (N + GV_VPB - 1) / GV_VPB;   // 157 blocks
    GaussianVoxelizer_40467181863368_kernel<<<grid_n, 256, 0, stream>>>(
        means, opac, feats, covs, out_dens, out_feat, N, G);
}

// Round 8
// 65.471 us; speedup vs baseline: 1.0263x; 1.0263x over previous
//
#include <hip/hip_runtime.h>
#include <hip/hip_bf16.h>

// GaussianVoxelizer: B=1, G=128 gaussians, F=16 features, N=100*100*8=80000.
// Sum/count formulation (== reference's incremental masked mean).
//
// R8 = revert to R6 (best measured: 65.2 us). R7's 2-voxel/thread variant
// halved block count and lost TLP (628 waves vs 1250) -> regressed; this
// kernel is latency-bound on the per-block setup chain, so more small
// blocks win.
//
// Design: single-launch gather + per-block cull + SURVIVOR-ONLY staging.
//  - 313 blocks x 256 threads, one voxel per thread.
//  - Cull reads only mean+cov (same 6 KB -> L2-hot). AABB half-width
//    2*sqrt(cov_ii)+eps is the exact support bound of {maha<=4} -> can
//    never exclude a true hit.
//  - Only survivors (avg ~1/block) compute the 3x3 inverse (adjugate,
//    -0.5 folded, off-diags pre-doubled), load features (float4), and write
//    params directly into compacted LDS slots (deterministic ascending-g
//    via ballot prefix-popcount).
//  - Eval loop over L compacted slots; LDS broadcast reads; no atomics;
//    unconditional coalesced stores; centers recomputed as (i+0.5)*0.8+lo,
//    bit-identical to the reference grid (grid_coords input unused).
//
// Inputs (setup_inputs order):
//   d_in[0] grid_coords (N,3) f32   (unused)
//   d_in[1] means3d     (1,G,3) f32
//   d_in[2] opacities   (1,G,1) f32
//   d_in[3] features    (1,G,F) f32
//   d_in[4] covariances (1,G,3,3) f32
// Output: dens (N) f32 followed by feats (N,F) f32, concatenated flat.

#define GV_F 16
#define GV_SX 100
#define GV_SY 100
#define GV_SZ 8
#define GV_SYZ (GV_SY * GV_SZ)   // 800
#define GV_LOX (-40.0f)
#define GV_LOY (-40.0f)
#define GV_LOZ (-1.0f)
#define GV_VOX 0.8f
#define GV_GMAX 128

__global__ __launch_bounds__(256)
void GaussianVoxelizer_40467181863368_kernel(
    const float* __restrict__ means,  // (G,3)
    const float* __restrict__ opac,   // (G)
    const float* __restrict__ feats,  // (G,F)
    const float* __restrict__ covs,   // (G,9)
    float* __restrict__ out_dens,     // (N)
    float* __restrict__ out_feat,     // (N,F)
    int N, int G)
{
    // compacted survivor params: [0..2]=mean, [3]=opacity,
    // [4..9]=k00,k01,k02,k11,k12,k22 (coeffs of -0.5*maha, off-diags doubled)
    __shared__ float s_p[GV_GMAX][10];
    __shared__ float s_f[GV_GMAX][GV_F];   // opacity * features (compacted)
    __shared__ unsigned long long s_mask[4];

    const int t = threadIdx.x;
    const int wv = t >> 6;
    const int n0 = blockIdx.x * 256;
    const int nlast = min(n0 + 255, N - 1);

    // ---- Block AABB over voxel CENTERS ----
    const int ix_lo = n0 / GV_SYZ;
    const int ix_hi = nlast / GV_SYZ;
    const float bx0 = ((float)ix_lo + 0.5f) * GV_VOX + GV_LOX;
    const float bx1 = ((float)ix_hi + 0.5f) * GV_VOX + GV_LOX;
    float by0, by1;
    if (ix_lo == ix_hi) {
        const int iy0b = (n0 - ix_lo * GV_SYZ) >> 3;          // /GV_SZ
        const int iy1b = (nlast - ix_hi * GV_SYZ) >> 3;
        by0 = ((float)iy0b + 0.5f) * GV_VOX + GV_LOY;
        by1 = ((float)iy1b + 0.5f) * GV_VOX + GV_LOY;
    } else {                                                   // straddles x boundary
        by0 = 0.5f * GV_VOX + GV_LOY;
        by1 = ((float)(GV_SY - 1) + 0.5f) * GV_VOX + GV_LOY;
    }
    const float bz0 = 0.5f * GV_VOX + GV_LOZ;                  // -0.6
    const float bz1 = ((float)(GV_SZ - 1) + 0.5f) * GV_VOX + GV_LOZ;  // 5.0

    // ---- Cull: mean + cov only (same 6 KB read by every block -> L2-hot) ----
    bool flag = false;
    float mx = 0.f, my = 0.f, mz = 0.f;
    float c00 = 0.f, c01 = 0.f, c02 = 0.f, c11 = 0.f, c12 = 0.f, c22 = 0.f;
    if (t < G) {
        mx = means[t * 3 + 0];
        my = means[t * 3 + 1];
        mz = means[t * 3 + 2];
        c00 = covs[t * 9 + 0];
        c01 = covs[t * 9 + 1];
        c02 = covs[t * 9 + 2];
        c11 = covs[t * 9 + 4];
        c12 = covs[t * 9 + 5];
        c22 = covs[t * 9 + 8];
        const float rx = 2.0f * sqrtf(c00) + 1e-3f;   // support bound + fp pad
        const float ry = 2.0f * sqrtf(c11) + 1e-3f;
        const float rz = 2.0f * sqrtf(c22) + 1e-3f;
        flag = (mx - rx <= bx1) && (mx + rx >= bx0) &&
               (my - ry <= by1) && (my + ry >= by0) &&
               (mz - rz <= bz1) && (mz + rz >= bz0);
    }

    const unsigned long long m = __ballot(flag);
    if ((t & 63) == 0) s_mask[wv] = m;
    __syncthreads();

    // ---- Survivor-only staging into compacted slots (ascending g) ----
    if (flag) {
        int pos = 0;
        #pragma unroll
        for (int i = 0; i < 4; ++i) pos += (i < wv) ? __popcll(s_mask[i]) : 0;
        const unsigned long long lt = (t & 63) ? ((1ull << (t & 63)) - 1ull) : 0ull;
        pos += __popcll(m & lt);

        // inverse covariance via adjugate (cov = A*A^T + 0.1I, SPD, det>=1e-3)
        const float m00 = c11 * c22 - c12 * c12;
        const float m01 = c02 * c12 - c01 * c22;
        const float m02 = c01 * c12 - c02 * c11;
        const float det = c00 * m00 + c01 * m01 + c02 * m02;
        const float s = -0.5f / det;
        const float op = opac[t];

        s_p[pos][0] = mx;
        s_p[pos][1] = my;
        s_p[pos][2] = mz;
        s_p[pos][3] = op;
        s_p[pos][4] = m00 * s;
        s_p[pos][5] = m01 * (2.0f * s);
        s_p[pos][6] = m02 * (2.0f * s);
        s_p[pos][7] = (c00 * c22 - c02 * c02) * s;
        s_p[pos][8] = (c01 * c02 - c00 * c12) * (2.0f * s);
        s_p[pos][9] = (c00 * c11 - c01 * c01) * s;

        const float4* fr = (const float4*)(feats + (size_t)t * GV_F);
        float4* fw = (float4*)(&s_f[pos][0]);
        #pragma unroll
        for (int q = 0; q < 4; ++q) {
            float4 v = fr[q];
            v.x *= op; v.y *= op; v.z *= op; v.w *= op;
            fw[q] = v;
        }
    }
    __syncthreads();
    const int L = __popcll(s_mask[0]) + __popcll(s_mask[1]) +
                  __popcll(s_mask[2]) + __popcll(s_mask[3]);

    // ---- Per-voxel evaluation over the compacted list ----
    const int n = n0 + t;
    if (n >= N) return;

    const int ix = n / GV_SYZ;
    const int rem = n - ix * GV_SYZ;
    const int iy = rem >> 3;
    const int iz = rem & 7;
    const float cx = ((float)ix + 0.5f) * GV_VOX + GV_LOX;
    const float cy = ((float)iy + 0.5f) * GV_VOX + GV_LOY;
    const float cz = ((float)iz + 0.5f) * GV_VOX + GV_LOZ;

    float cnt = 0.0f;
    float sum_d = 0.0f;
    float sum_f[GV_F];
    #pragma unroll
    for (int j = 0; j < GV_F; ++j) sum_f[j] = 0.0f;

    for (int l = 0; l < L; ++l) {               // l block-uniform -> LDS broadcast
        const float dx = cx - s_p[l][0];
        const float dy = cy - s_p[l][1];
        const float dz = cz - s_p[l][2];
        // tt = -0.5 * maha
        float a = s_p[l][4] * dx;
        a = fmaf(s_p[l][5], dy, a);
        a = fmaf(s_p[l][6], dz, a);
        float tt = a * dx;
        float b = s_p[l][7] * dy;
        b = fmaf(s_p[l][8], dz, b);
        tt = fmaf(b, dy, tt);
        tt = fmaf(s_p[l][9] * dz, dz, tt);
        if (tt >= -2.0f) {                      // maha <= 4
            const float w = __expf(tt);
            cnt += 1.0f;
            sum_d = fmaf(s_p[l][3], w, sum_d);
            #pragma unroll
            for (int j = 0; j < GV_F; ++j) sum_f[j] = fmaf(s_f[l][j], w, sum_f[j]);
        }
    }

    const float inv_c = (cnt > 0.0f) ? (1.0f / cnt) : 0.0f;
    out_dens[n] = sum_d * inv_c;
    float4* fo = (float4*)(out_feat + (size_t)n * GV_F);
    #pragma unroll
    for (int q = 0; q < 4; ++q) {
        fo[q] = make_float4(sum_f[4 * q + 0] * inv_c,
                            sum_f[4 * q + 1] * inv_c,
                            sum_f[4 * q + 2] * inv_c,
                            sum_f[4 * q + 3] * inv_c);
    }
}

extern "C" void kernel_launch(void* const* d_in, const int* in_sizes, int n_in,
                              void* d_out, int out_size, void* d_ws, size_t ws_size,
                              hipStream_t stream) {
    const float* means = (const float*)d_in[1];
    const float* opac  = (const float*)d_in[2];
    const float* feats = (const float*)d_in[3];
    const float* covs  = (const float*)d_in[4];

    const int N = in_sizes[0] / 3;       // 80000
    const int G = in_sizes[2];           // B*G = 128 (B=1)

    float* out_dens = (float*)d_out;         // (N)
    float* out_feat = (float*)d_out + N;     // (N,F)

    const int grid_n = (N + 255) / 256;      // 313 blocks
    GaussianVoxelizer_40467181863368_kernel<<<grid_n, 256, 0, stream>>>(
        means, opac, feats, covs, out_dens, out_feat, N, G);
}